// Round 1
// 110.101 us; speedup vs baseline: 1.0228x; 1.0228x over previous
//
#include <hip/hip_runtime.h>

// Problem constants
constexpr int Bb = 1024;   // batch
constexpr int Ii = 256;    // in features
constexpr int Oo = 256;    // out features
constexpr int Kk = 128;    // knots
constexpr int NCH = 8;     // i-chunks (XCD-aligned)

typedef unsigned short u16;
typedef unsigned int u32;
typedef u16 ushort4v __attribute__((ext_vector_type(4)));
typedef float f4v __attribute__((ext_vector_type(4)));

__device__ __forceinline__ float bf16u_to_f(u16 u) {
    union { u32 ui; float f; } c;
    c.ui = ((u32)u) << 16;
    return c.f;
}
__device__ __forceinline__ u16 f_to_bf16(float f) {  // round-to-nearest-even
    union { float f; u32 u; } c; c.f = f;
    u32 r = c.u + 0x7fffu + ((c.u >> 16) & 1u);
    return (u16)(r >> 16);
}

// Kernel A: permute+scale Cs[o][i][k] -> Cp[i][k][o] bf16 via LDS transpose.
// XCD-aligned numbering (chunk = blk & 7) so chunk c's 2 MB Cp slice is
// written by XCD c and stays dirty-resident in XCD c's L2 for kmain.
// NEW: cs reads are NON-TEMPORAL (32 MB read-once stream; 4 MB/XCD would
// otherwise LRU-evict the 2 MB cp slice out of the 4 MB per-XCD L2 before
// kmain's gathers arrive). wbase tail reads likewise nt (read-once,
// line-overfetched gather — keep it out of L2).
__global__ __launch_bounds__(256) void kperm(const float* __restrict__ cs,
                                             const float* __restrict__ scale,
                                             const float* __restrict__ wbase,
                                             u16* __restrict__ cp,
                                             float* __restrict__ wt) {
    __shared__ u16 T[128 * 66];       // [o_local][k_local], pitch 66
    int blk = blockIdx.x;
    int chunk = blk & 7;
    int sub = blk >> 3;               // 0..127
    int i  = chunk * 32 + (sub & 31); // i within this XCD's chunk
    int oh = (sub >> 5) & 1, kh = (sub >> 6) & 1;
    int o0 = oh << 7, kb = kh << 6;
    int t = threadIdx.x;

    // Phase 1: load Cs rows (float4 along k, nt), scale, bf16 -> LDS
    {
        int c4 = t & 15;              // float4 index within the 64-k half
        int rb = t >> 4;              // 0..15
        const f4v* cs4 = (const f4v*)cs;
#pragma unroll
        for (int p = 0; p < 8; ++p) {
            int r = p * 16 + rb;      // o_local 0..127
            int o = o0 + r;
            float sc = scale[o * Ii + i];   // shared across 16 same-XCD blocks: keep cached
            f4v val = __builtin_nontemporal_load(
                &cs4[(size_t)(o * Ii + i) * (Kk / 4) + kh * 16 + c4]);
            int kl = c4 * 4;
            T[r * 66 + kl + 0] = f_to_bf16(val.x * sc);
            T[r * 66 + kl + 1] = f_to_bf16(val.y * sc);
            T[r * 66 + kl + 2] = f_to_bf16(val.z * sc);
            T[r * 66 + kl + 3] = f_to_bf16(val.w * sc);
        }
    }
    __syncthreads();
    // Phase 2: write Cp[i][kb+kl][o0..o0+128], lanes <-> o (u32 = 2 o)
    // Normal (allocating) stores: these MUST land + stay in local L2.
    {
        int og = t & 63;              // o-pair index (o = og*2, og*2+1)
        int kg = t >> 6;              // 0..3, 16 k-rows each
#pragma unroll
        for (int m = 0; m < 16; ++m) {
            int kl = kg * 16 + m;
            u32 lo = T[(og * 2) * 66 + kl];
            u32 hi = T[(og * 2 + 1) * 66 + kl];
            *(u32*)&cp[((size_t)i * Kk + kb + kl) * Oo + o0 + og * 2] = lo | (hi << 16);
        }
    }
    // Tail: Wt[i][o] = W[o][i] (65536 elems across blocks 0..255)
    if (blk < 256) {
        int gid = blk * 256 + t;
        wt[gid] = __builtin_nontemporal_load(&wbase[(gid & 255) * Ii + (gid >> 8)]);
    }
}

// Kernel B: main accumulation. 1024 blocks = 128 b-tiles (8 b) x 8 i-chunks
// (32 i); exactly 4 blocks/CU. NEW structure vs R11:
//  - ALL 32 wt rows staged up-front as coalesced float4 (32 KB LDS), so the
//    main loop has ZERO barriers (was 8 per block) and waves run free —
//    better cross-wave latency hiding for the L2 gathers.
//  - x read non-temporal (read-once).
// LDS = 4 KB sf + 32 KB wbuf = 36 KB -> still 4 blocks/CU (147 KB < 160 KB).
__global__ __launch_bounds__(256, 4) void kmain(const float* __restrict__ x,
                                                const char* __restrict__ cpb,
                                                const float* __restrict__ wt,
                                                float4* __restrict__ part4) {
    __shared__ float4 sf[256];           // [il][bl] : 32 i x 8 b   (4 KB)
    __shared__ float wbuf[32 * 256];     // all 32 i-rows of w      (32 KB)
    int t = threadIdx.x;
    int blk = blockIdx.x;
    int chunk = blk & (NCH - 1);
    int b0 = (blk >> 3) << 3;            // b-tile * 8
    int i0 = chunk << 5;                 // 32 i per chunk

    {                                    // prep: 1 (b,i) per thread
        int il = t & 31, bl = t >> 5;    // coalesced x reads along il
        float xv = __builtin_nontemporal_load(
            &x[(size_t)(b0 + bl) * Ii + i0 + il]);
        float e2 = __expf(2.f * xv);
        float p = 1.f - 2.f / (e2 + 1.f);   // tanh
        float s = p / (1.f + __expf(-p));   // silu(p)
        float c = fminf(fmaxf(p, -1.f), 1.f);
        float scaled = (c + 1.f) * ((float)(Kk - 1) * 0.5f);
        int l = (int)floorf(scaled);
        l = min(max(l, 0), Kk - 1);
        int rr = min(l + 1, Kk - 1);
        float4 v;
        v.x = scaled - (float)l;             // frac
        v.y = s;                             // silu
        v.z = __int_as_float(l * (Oo * 2));  // byte ofs, left row in [k][o] slab
        v.w = __int_as_float(rr * (Oo * 2)); // byte ofs, right row
        sf[il * 8 + bl] = v;
    }
    {                                    // stage all 32 w-rows, float4-coalesced
        const float4* wsrc4 = (const float4*)(wt + (size_t)i0 * Oo);
        float4* wb4 = (float4*)wbuf;
#pragma unroll
        for (int p = 0; p < 8; ++p)
            wb4[t + p * 256] = wsrc4[t + p * 256];
    }
    __syncthreads();                     // the ONLY barrier

    int oq = t & 63;                     // o = oq*4 .. oq*4+3
    int bq = t >> 6;                     // 0..3 -> b = b0 + bq*2 + {0,1}

    float a00=0.f,a01=0.f,a02=0.f,a03=0.f;   // b = b0 + bq*2
    float a10=0.f,a11=0.f,a12=0.f,a13=0.f;   // b = b0 + bq*2 + 1
    const char* cbase = cpb + (size_t)i0 * (Kk * Oo * 2) + oq * 8;

#pragma unroll 4
    for (int m = 0; m < 32; ++m) {
        float4 v0 = sf[m * 8 + bq * 2];              // LDS broadcast
        float4 v1 = sf[m * 8 + bq * 2 + 1];
        float4 w = *(const float4*)&wbuf[m * 256 + oq * 4];  // b128, no conflicts
        const char* ci = cbase + (size_t)m * (Kk * Oo * 2);
        ushort4v cl0 = *(const ushort4v*)(ci + __float_as_int(v0.z));
        ushort4v cr0 = *(const ushort4v*)(ci + __float_as_int(v0.w));
        ushort4v cl1 = *(const ushort4v*)(ci + __float_as_int(v1.z));
        ushort4v cr1 = *(const ushort4v*)(ci + __float_as_int(v1.w));
        float f0 = v0.x, g0 = 1.f - v0.x, s0 = v0.y;
        float f1 = v1.x, g1 = 1.f - v1.x, s1 = v1.y;
        a00 = fmaf(s0, w.x, a00); a01 = fmaf(s0, w.y, a01);
        a02 = fmaf(s0, w.z, a02); a03 = fmaf(s0, w.w, a03);
        a10 = fmaf(s1, w.x, a10); a11 = fmaf(s1, w.y, a11);
        a12 = fmaf(s1, w.z, a12); a13 = fmaf(s1, w.w, a13);
        a00 = fmaf(g0, bf16u_to_f(cl0.x), a00); a00 = fmaf(f0, bf16u_to_f(cr0.x), a00);
        a01 = fmaf(g0, bf16u_to_f(cl0.y), a01); a01 = fmaf(f0, bf16u_to_f(cr0.y), a01);
        a02 = fmaf(g0, bf16u_to_f(cl0.z), a02); a02 = fmaf(f0, bf16u_to_f(cr0.z), a02);
        a03 = fmaf(g0, bf16u_to_f(cl0.w), a03); a03 = fmaf(f0, bf16u_to_f(cr0.w), a03);
        a10 = fmaf(g1, bf16u_to_f(cl1.x), a10); a10 = fmaf(f1, bf16u_to_f(cr1.x), a10);
        a11 = fmaf(g1, bf16u_to_f(cl1.y), a11); a11 = fmaf(f1, bf16u_to_f(cr1.y), a11);
        a12 = fmaf(g1, bf16u_to_f(cl1.z), a12); a12 = fmaf(f1, bf16u_to_f(cr1.z), a12);
        a13 = fmaf(g1, bf16u_to_f(cl1.w), a13); a13 = fmaf(f1, bf16u_to_f(cr1.w), a13);
    }

    size_t cstride = (size_t)(Bb * Oo / 4);
    float4 r0; r0.x=a00; r0.y=a01; r0.z=a02; r0.w=a03;
    float4 r1; r1.x=a10; r1.y=a11; r1.z=a12; r1.w=a13;
    part4[chunk * cstride + (size_t)(b0 + bq * 2) * (Oo / 4) + oq] = r0;
    part4[chunk * cstride + (size_t)(b0 + bq * 2 + 1) * (Oo / 4) + oq] = r1;
}

// Kernel C: out[b][o] = bias[o] + sum_c partial[c][b][o]. 256 blocks.
// Partials read non-temporal (read-once stream).
__global__ __launch_bounds__(256) void kreduce(const float4* __restrict__ part4,
                                               const float4* __restrict__ bias4,
                                               float4* __restrict__ out4) {
    int gid = blockIdx.x * 256 + threadIdx.x;     // = b*64 + o4
    const f4v* p = (const f4v*)(part4 + gid);
    f4v s = __builtin_nontemporal_load(p);
#pragma unroll
    for (int c = 1; c < NCH; ++c) {
        f4v v = __builtin_nontemporal_load(p + (size_t)c * (Bb * Oo / 4));
        s.x += v.x; s.y += v.y; s.z += v.z; s.w += v.w;
    }
    float4 bv = bias4[gid & 63];
    float4 o;
    o.x = s.x + bv.x; o.y = s.y + bv.y; o.z = s.z + bv.z; o.w = s.w + bv.w;
    out4[gid] = o;
}

extern "C" void kernel_launch(void* const* d_in, const int* in_sizes, int n_in,
                              void* d_out, int out_size, void* d_ws, size_t ws_size,
                              hipStream_t stream) {
    const float* x     = (const float*)d_in[0];
    const float* wbase = (const float*)d_in[1];
    const float* coeff = (const float*)d_in[2];
    const float* scale = (const float*)d_in[3];
    const float* bias  = (const float*)d_in[4];
    float* out = (float*)d_out;

    char* ws = (char*)d_ws;
    u16*    cp    = (u16*)ws;                             // 16 MB @ 0
    float*  wt    = (float*)(ws + (16u << 20));           // 256 KB @ 16M
    float4* part4 = (float4*)(ws + (17u << 20));          // 8 MB @ 17M

    kperm<<<1024, 256, 0, stream>>>(coeff, scale, wbase, cp, wt);
    kmain<<<1024, 256, 0, stream>>>(x, (const char*)cp, wt, part4);
    kreduce<<<(Bb * Oo / 4) / 256, 256, 0, stream>>>(part4, (const float4*)bias, (float4*)out);
}